// Round 9
// baseline (190.866 us; speedup 1.0000x reference)
//
#include <hip/hip_runtime.h>
#include <hip/hip_bf16.h>

// GAT layer, N=8192 Fin=256 Fout=64.
// k1: Wh = h@W, s1/s2 = Wh@a halves (s2 pre-scaled by log2e), whT hi/lo bf16.
// k2 v8: TLP-first fused attention.
//   R2-R8 lesson: three different pipelining structures all stalled at ~197us
//   because grid=256 = 1 block/CU = 2 waves/SIMD. Fix the launch shape:
//   - grid 1024 = (qi row-tile) x (jq j-quarter); 256-thr blocks (4 waves).
//   - each wave does BOTH feature halves (P-compute amortized, adj read once).
//   - partial (unnormalized acc, denom) accumulated cross-block via atomicAdd;
//     k3 finishes div + ELU.
//   - plain compiler-scheduled loads; 16 waves/CU hides latency via TLP.
//   - P computed per-thread directly in mfma_f32_32x32x16_bf16 B-frag layout;
//     fixed row-max bound m=lrelu(s1+16); 3-MFMA bf16 hi/lo split per half.

typedef __attribute__((ext_vector_type(8))) short bf16x8;
typedef __attribute__((ext_vector_type(16))) float f32x16;

#define LOG2E 1.4426950408889634f

__device__ __forceinline__ uint pk2(float a, float b, float& ra, float& rb) {
    __hip_bfloat162 h = __float22bfloat162_rn(make_float2(a, b));
    float2 f = __bfloat1622float2(h);
    ra = f.x; rb = f.y;
    union { __hip_bfloat162 b; uint u; } c; c.b = h; return c.u;
}
__device__ __forceinline__ uint pk2o(float a, float b) {
    __hip_bfloat162 h = __float22bfloat162_rn(make_float2(a, b));
    union { __hip_bfloat162 b; uint u; } c; c.b = h; return c.u;
}
__device__ __forceinline__ ushort f2bf(float x) {
    union { __hip_bfloat16 b; ushort u; } c;
    c.b = __float2bfloat16(x);
    return c.u;
}
__device__ __forceinline__ float bf2f(ushort u) {
    union { ushort u; __hip_bfloat16 b; } c;
    c.u = u;
    return __bfloat162float(c.b);
}

// ---------------- kernel 1: Wh, s1, s2*log2e, WhT hi/lo ----------------
__global__ __launch_bounds__(256) void k1_wh(
    const float* __restrict__ h, const float* __restrict__ W,
    const float* __restrict__ a,
    float* __restrict__ s1, float* __restrict__ s2,
    ushort* __restrict__ whT_hi, ushort* __restrict__ whT_lo)
{
    const int l = threadIdx.x & 63;      // lane = output feature
    const int w = threadIdx.x >> 6;
    const int row0 = blockIdx.x * 16 + w * 4;

    float acc[4] = {0.f, 0.f, 0.f, 0.f};
    for (int k = 0; k < 256; k += 4) {
        float w0 = W[(k + 0) * 64 + l];
        float w1 = W[(k + 1) * 64 + l];
        float w2 = W[(k + 2) * 64 + l];
        float w3 = W[(k + 3) * 64 + l];
#pragma unroll
        for (int r = 0; r < 4; ++r) {
            const float4 hv = *reinterpret_cast<const float4*>(&h[(row0 + r) * 256 + k]);
            acc[r] = fmaf(hv.x, w0, acc[r]);
            acc[r] = fmaf(hv.y, w1, acc[r]);
            acc[r] = fmaf(hv.z, w2, acc[r]);
            acc[r] = fmaf(hv.w, w3, acc[r]);
        }
    }
    const float a1 = a[l];
    const float a2 = a[64 + l];
#pragma unroll
    for (int r = 0; r < 4; ++r) {
        const int row = row0 + r;
        float x1 = acc[r] * a1;
        float x2 = acc[r] * a2;
#pragma unroll
        for (int m = 32; m >= 1; m >>= 1) {
            x1 += __shfl_xor(x1, m);
            x2 += __shfl_xor(x2, m);
        }
        if (l == 0) { s1[row] = x1; s2[row] = x2 * LOG2E; }
        const ushort hi = f2bf(acc[r]);
        const ushort lo = f2bf(acc[r] - bf2f(hi));
        whT_hi[l * 8192 + row] = hi;
        whT_lo[l * 8192 + row] = lo;
    }
}

// ---------------- kernel 2: TLP fused attention (partial sums) ----------------

// t1,t2 in log2 domain (s2 pre-scaled by log2e in k1)
#define PEXP(dst, a_, s_) { \
    const float t1_ = A + (s_); \
    const float t2_ = fmaf(0.2f, (s_), A5); \
    dst = __builtin_amdgcn_exp2f(fmaxf(t1_, t2_)); \
    if ((a_) <= 0) dst = 0.0f; \
    rs += dst; }

__global__ __launch_bounds__(256, 4) void k2_attn(
    const int* __restrict__ adj,
    const float* __restrict__ s1g, const float* __restrict__ s2g,
    const ushort* __restrict__ whT_hi, const ushort* __restrict__ whT_lo,
    float* __restrict__ pacc, float* __restrict__ pden)
{
    __shared__ __align__(16) float slds[3][2][64][16];   // ksub 1..3 partials (both ft)
    __shared__ float dlds[4][32];

    const int t   = threadIdx.x;
    const int l   = t & 63;
    const int wv  = t >> 6;           // ksub 0..3 (512 j each)
    const int bid = blockIdx.x;
    const int qi  = bid >> 2;         // row-tile 0..255
    const int jq  = bid & 3;          // j-quarter 0..3
    const int i0  = qi * 32;
    const int row = l & 31;           // node-row = B-frag col
    const int kh  = l >> 5;           // k-half within fragment
    const int jbase = jq * 2048 + wv * 512;

    const float s1v = s1g[i0 + row];
    const float mq  = s1v + 16.0f;
    const float m   = fmaxf(mq, 0.2f * mq);       // fixed row-max upper bound
    const float A   = (s1v - m) * LOG2E;
    const float A5  = fmaf(0.2f, s1v, -m) * LOG2E;

    const int*    aptr = adj    + (size_t)(i0 + row) * 8192 + jbase + kh * 8;
    const float*  sptr = s2g    + jbase + kh * 8;
    const ushort* h0p  = whT_hi + (size_t)row * 8192        + jbase + kh * 8;
    const ushort* l0p  = whT_lo + (size_t)row * 8192        + jbase + kh * 8;
    const ushort* h1p  = whT_hi + (size_t)(32 + row) * 8192 + jbase + kh * 8;
    const ushort* l1p  = whT_lo + (size_t)(32 + row) * 8192 + jbase + kh * 8;

    f32x16 acc0 = {0.f,0.f,0.f,0.f,0.f,0.f,0.f,0.f,0.f,0.f,0.f,0.f,0.f,0.f,0.f,0.f};
    f32x16 acc1 = {0.f,0.f,0.f,0.f,0.f,0.f,0.f,0.f,0.f,0.f,0.f,0.f,0.f,0.f,0.f,0.f};
    float rs = 0.f;

#pragma unroll 2
    for (int T = 0; T < 32; ++T) {
        const size_t o = (size_t)T * 16;
        const int4   aA = *reinterpret_cast<const int4*>(aptr + o);
        const int4   aB = *reinterpret_cast<const int4*>(aptr + o + 4);
        const float4 sA = *reinterpret_cast<const float4*>(sptr + o);
        const float4 sB = *reinterpret_cast<const float4*>(sptr + o + 4);
        const bf16x8 h0 = *reinterpret_cast<const bf16x8*>(h0p + o);
        const bf16x8 l0 = *reinterpret_cast<const bf16x8*>(l0p + o);
        const bf16x8 h1 = *reinterpret_cast<const bf16x8*>(h1p + o);
        const bf16x8 l1 = *reinterpret_cast<const bf16x8*>(l1p + o);

        float p0,p1,p2,p3,p4,p5,p6,p7, r0,r1,r2,r3,r4,r5,r6,r7;
        PEXP(p0, aA.x, sA.x)
        PEXP(p1, aA.y, sA.y)
        PEXP(p2, aA.z, sA.z)
        PEXP(p3, aA.w, sA.w)
        PEXP(p4, aB.x, sB.x)
        PEXP(p5, aB.y, sB.y)
        PEXP(p6, aB.z, sB.z)
        PEXP(p7, aB.w, sB.w)

        union PKU { bf16x8 v; uint u[4]; } bh_, bl_;
        bh_.u[0] = pk2(p0, p1, r0, r1);
        bh_.u[1] = pk2(p2, p3, r2, r3);
        bh_.u[2] = pk2(p4, p5, r4, r5);
        bh_.u[3] = pk2(p6, p7, r6, r7);
        bl_.u[0] = pk2o(p0 - r0, p1 - r1);
        bl_.u[1] = pk2o(p2 - r2, p3 - r3);
        bl_.u[2] = pk2o(p4 - r4, p5 - r5);
        bl_.u[3] = pk2o(p6 - r6, p7 - r7);

        acc0 = __builtin_amdgcn_mfma_f32_32x32x16_bf16(h0, bh_.v, acc0, 0, 0, 0);
        acc0 = __builtin_amdgcn_mfma_f32_32x32x16_bf16(h0, bl_.v, acc0, 0, 0, 0);
        acc0 = __builtin_amdgcn_mfma_f32_32x32x16_bf16(l0, bh_.v, acc0, 0, 0, 0);
        acc1 = __builtin_amdgcn_mfma_f32_32x32x16_bf16(h1, bh_.v, acc1, 0, 0, 0);
        acc1 = __builtin_amdgcn_mfma_f32_32x32x16_bf16(h1, bl_.v, acc1, 0, 0, 0);
        acc1 = __builtin_amdgcn_mfma_f32_32x32x16_bf16(l1, bh_.v, acc1, 0, 0, 0);
    }

    // ---- epilogue: combine 4 ksub-partials within the block ----
    rs += __shfl_xor(rs, 32);               // lanes l, l+32 hold same row
    if (kh == 0) dlds[wv][row] = rs;
    if (wv != 0) {
        float4* d0 = reinterpret_cast<float4*>(&slds[wv - 1][0][l][0]);
        float4* d1 = reinterpret_cast<float4*>(&slds[wv - 1][1][l][0]);
#pragma unroll
        for (int g = 0; g < 4; ++g) {
            d0[g] = make_float4(acc0[g*4+0], acc0[g*4+1], acc0[g*4+2], acc0[g*4+3]);
            d1[g] = make_float4(acc1[g*4+0], acc1[g*4+1], acc1[g*4+2], acc1[g*4+3]);
        }
    }
    __syncthreads();
    if (wv == 0) {
#pragma unroll
        for (int s = 0; s < 3; ++s) {
            const float4* s0 = reinterpret_cast<const float4*>(&slds[s][0][l][0]);
            const float4* s1 = reinterpret_cast<const float4*>(&slds[s][1][l][0]);
#pragma unroll
            for (int g = 0; g < 4; ++g) {
                const float4 v0 = s0[g], v1 = s1[g];
                acc0[g*4+0] += v0.x; acc0[g*4+1] += v0.y; acc0[g*4+2] += v0.z; acc0[g*4+3] += v0.w;
                acc1[g*4+0] += v1.x; acc1[g*4+1] += v1.y; acc1[g*4+2] += v1.z; acc1[g*4+3] += v1.w;
            }
        }
        const float den = dlds[0][row] + dlds[1][row] + dlds[2][row] + dlds[3][row];
        if (kh == 0) atomicAdd(&pden[i0 + row], den);
        // D layout (32x32): col=l&31 -> node row; feat-in-half = j + 8g + 4kh
        float* pb = pacc + (size_t)(i0 + row) * 64;
#pragma unroll
        for (int g = 0; g < 4; ++g) {
#pragma unroll
            for (int j = 0; j < 4; ++j) {
                const int f = j + 8 * g + 4 * kh;
                atomicAdd(pb + f,      acc0[g*4+j]);
                atomicAdd(pb + 32 + f, acc1[g*4+j]);
            }
        }
    }
}

// ---------------- kernel 3: finish (divide + ELU) ----------------
__global__ __launch_bounds__(256) void k3_fin(
    const float* __restrict__ pacc, const float* __restrict__ pden,
    float* __restrict__ out)
{
    const int idx = blockIdx.x * 256 + threadIdx.x;   // 131072 float4-groups
    const int row = idx >> 4;
    const float inv = 1.0f / pden[row];
    const float4 v = reinterpret_cast<const float4*>(pacc)[idx];
    float4 o; float x;
    x = v.x * inv; o.x = (x > 0.f) ? x : expm1f(x);
    x = v.y * inv; o.y = (x > 0.f) ? x : expm1f(x);
    x = v.z * inv; o.z = (x > 0.f) ? x : expm1f(x);
    x = v.w * inv; o.w = (x > 0.f) ? x : expm1f(x);
    reinterpret_cast<float4*>(out)[idx] = o;
}

extern "C" void kernel_launch(void* const* d_in, const int* in_sizes, int n_in,
                              void* d_out, int out_size, void* d_ws, size_t ws_size,
                              hipStream_t stream) {
    const float* h   = (const float*)d_in[0];
    const int*   adj = (const int*)d_in[1];
    const float* W   = (const float*)d_in[2];
    const float* a   = (const float*)d_in[3];
    float* out = (float*)d_out;

    float*  s1     = (float*)d_ws;                 // 8192 f32
    float*  s2     = s1 + 8192;                    // 8192 f32 (pre-scaled log2e)
    ushort* whT_hi = (ushort*)(s2 + 8192);         // [64][8192] bf16
    ushort* whT_lo = whT_hi + 64 * 8192;           // [64][8192] bf16
    float*  pacc   = (float*)(whT_lo + 64 * 8192); // [8192][64] f32 partial acc
    float*  pden   = pacc + 8192 * 64;             // [8192] f32 partial denom

    hipMemsetAsync(pacc, 0, (8192 * 64 + 8192) * sizeof(float), stream);
    hipLaunchKernelGGL(k1_wh, dim3(512), dim3(256), 0, stream,
                       h, W, a, s1, s2, whT_hi, whT_lo);
    hipLaunchKernelGGL(k2_attn, dim3(1024), dim3(256), 0, stream,
                       adj, s1, s2, whT_hi, whT_lo, pacc, pden);
    hipLaunchKernelGGL(k3_fin, dim3(512), dim3(256), 0, stream,
                       pacc, pden, out);
}

// Round 10
// 133.290 us; speedup vs baseline: 1.4320x; 1.4320x over previous
//
#include <hip/hip_runtime.h>
#include <hip/hip_bf16.h>

// GAT layer, N=8192 Fin=256 Fout=64.
// R9 post-mortem: all loads were 32-line gathers (lane<->row stride 8192);
// kernel was transaction-throughput-bound (~190us invariant across ILP/TLP).
// v9: every global load is line-coalesced.
//   k1: Wh=h@W; s1/s2 (s2 pre-scaled log2e); whT hi/lo packed as MFMA A-frags
//       PW[jstep][ft][lane] via LDS transpose -> k2 A-loads are 1KB contiguous.
//   k2: grid 1024 (qi x jq), 4 waves; adj loaded lane<->j coalesced
//       (128B/row-octet), P computed in coalesced layout, transposed to B-frag
//       layout through wave-private LDS (pitch-36 ushort rows ~ bank floor).
//       P-hi only (error ~2^-9*|Wh| ~ 0.004 << 0.0145); whT keeps hi/lo.
//       Partial acc/denoms -> atomicAdd; k3 finishes div+ELU.

typedef __attribute__((ext_vector_type(8))) short bf16x8;
typedef __attribute__((ext_vector_type(16))) float f32x16;

#define LOG2E 1.4426950408889634f

__device__ __forceinline__ uint pk2o(float a, float b) {
    __hip_bfloat162 h = __float22bfloat162_rn(make_float2(a, b));
    union { __hip_bfloat162 b; uint u; } c; c.b = h; return c.u;
}
__device__ __forceinline__ ushort f2bf(float x) {
    union { __hip_bfloat16 b; ushort u; } c;
    c.b = __float2bfloat16(x);
    return c.u;
}
__device__ __forceinline__ float bf2f(ushort u) {
    union { ushort u; __hip_bfloat16 b; } c;
    c.u = u;
    return __bfloat162float(c.b);
}

// ---------------- kernel 1: Wh, s1, s2*log2e, packed A-frags ----------------
// grid 512: block b -> Wh rows 16b..16b+15 (= jstep b), all 64 feats.
__global__ __launch_bounds__(256) void k1_wh(
    const float* __restrict__ h, const float* __restrict__ W,
    const float* __restrict__ a,
    float* __restrict__ s1, float* __restrict__ s2,
    ushort* __restrict__ pw_hi, ushort* __restrict__ pw_lo)
{
    __shared__ ushort whh[16][64], whl[16][64];
    const int l = threadIdx.x & 63;      // lane = output feature
    const int w = threadIdx.x >> 6;
    const int b = blockIdx.x;
    const int row0 = b * 16 + w * 4;

    float acc[4] = {0.f, 0.f, 0.f, 0.f};
    for (int k = 0; k < 256; k += 4) {
        float w0 = W[(k + 0) * 64 + l];
        float w1 = W[(k + 1) * 64 + l];
        float w2 = W[(k + 2) * 64 + l];
        float w3 = W[(k + 3) * 64 + l];
#pragma unroll
        for (int r = 0; r < 4; ++r) {
            const float4 hv = *reinterpret_cast<const float4*>(&h[(row0 + r) * 256 + k]);
            acc[r] = fmaf(hv.x, w0, acc[r]);
            acc[r] = fmaf(hv.y, w1, acc[r]);
            acc[r] = fmaf(hv.z, w2, acc[r]);
            acc[r] = fmaf(hv.w, w3, acc[r]);
        }
    }
    const float a1 = a[l];
    const float a2 = a[64 + l];
#pragma unroll
    for (int r = 0; r < 4; ++r) {
        const int row = row0 + r;
        float x1 = acc[r] * a1;
        float x2 = acc[r] * a2;
#pragma unroll
        for (int m = 32; m >= 1; m >>= 1) {
            x1 += __shfl_xor(x1, m);
            x2 += __shfl_xor(x2, m);
        }
        if (l == 0) { s1[row] = x1; s2[row] = x2 * LOG2E; }
        const ushort hi = f2bf(acc[r]);
        const ushort lo = f2bf(acc[r] - bf2f(hi));
        whh[w * 4 + r][l] = hi;
        whl[w * 4 + r][l] = lo;
    }
    __syncthreads();
    // PW[jstep=b][ft][lane l] = wh[(l>>5)*8+e][ft*32+(l&31)], e=0..7
    // waves 0,1 -> pw_hi (ft=w); waves 2,3 -> pw_lo (ft=w-2)
    const int ft = w & 1;
    const ushort (*src)[64] = (w < 2) ? whh : whl;
    ushort* dst = (w < 2) ? pw_hi : pw_lo;
    const int hh = l >> 5;
    union { bf16x8 v; ushort s[8]; } fr;
#pragma unroll
    for (int e = 0; e < 8; ++e)
        fr.s[e] = src[hh * 8 + e][ft * 32 + (l & 31)];
    *reinterpret_cast<bf16x8*>(&dst[(size_t)(b * 2 + ft) * 512 + l * 8]) = fr.v;
}

// ---------------- kernel 2: coalesced fused attention ----------------

#define PGRP(G, AV, RS) { \
    float t1_, t2_, p0_, p1_, p2_, p3_; \
    t1_ = Ag[G] + sv.x; t2_ = fmaf(0.2f, sv.x, A5g[G]); \
    p0_ = __builtin_amdgcn_exp2f(fmaxf(t1_, t2_)); if ((AV).x <= 0) p0_ = 0.f; \
    t1_ = Ag[G] + sv.y; t2_ = fmaf(0.2f, sv.y, A5g[G]); \
    p1_ = __builtin_amdgcn_exp2f(fmaxf(t1_, t2_)); if ((AV).y <= 0) p1_ = 0.f; \
    t1_ = Ag[G] + sv.z; t2_ = fmaf(0.2f, sv.z, A5g[G]); \
    p2_ = __builtin_amdgcn_exp2f(fmaxf(t1_, t2_)); if ((AV).z <= 0) p2_ = 0.f; \
    t1_ = Ag[G] + sv.w; t2_ = fmaf(0.2f, sv.w, A5g[G]); \
    p3_ = __builtin_amdgcn_exp2f(fmaxf(t1_, t2_)); if ((AV).w <= 0) p3_ = 0.f; \
    RS += (p0_ + p1_) + (p2_ + p3_); \
    *reinterpret_cast<uint2*>(&myp[(8 * (G) + g8) * 36 + jc]) = \
        make_uint2(pk2o(p0_, p1_), pk2o(p2_, p3_)); \
}

__global__ __launch_bounds__(256, 4) void k2_attn(
    const int* __restrict__ adj,
    const float* __restrict__ s1g, const float* __restrict__ s2g,
    const ushort* __restrict__ pw_hi, const ushort* __restrict__ pw_lo,
    float* __restrict__ pacc, float* __restrict__ pden)
{
    // smem: [0,8192) s2 quarter (f32) | [8192,+4*4608) per-wave P tiles
    // epilogue aliases [0, 24576) as slds[3][2][64][16] f32
    __shared__ __align__(16) unsigned char smem[8192 + 4 * 4608];

    const int t   = threadIdx.x;
    const int l   = t & 63;
    const int wv  = t >> 6;
    const int qi  = blockIdx.x >> 2;
    const int jq  = blockIdx.x & 3;
    const int i0  = qi * 32;
    const int row = l & 31;           // B-frag row (MFMA role)
    const int kh  = l >> 5;           // k-half (MFMA role)
    const int g8  = l >> 3;           // row-in-octet (P role)
    const int jc  = (l & 7) * 4;      // j-offset  (P role)

    // stage s2 quarter (coalesced)
    {
        const float4* src = reinterpret_cast<const float4*>(s2g + jq * 2048);
        float4* dst = reinterpret_cast<float4*>(smem);
        dst[t] = src[t];
        dst[t + 256] = src[t + 256];
    }
    // per-lane A-coeffs for its 4 row-octets
    float Ag[4], A5g[4];
#pragma unroll
    for (int g = 0; g < 4; ++g) {
        const float s1v = s1g[i0 + 8 * g + g8];
        const float mq  = s1v + 16.0f;
        const float m   = fmaxf(mq, 0.2f * mq);
        Ag[g]  = (s1v - m) * LOG2E;
        A5g[g] = fmaf(0.2f, s1v, -m) * LOG2E;
    }
    __syncthreads();

    const float* s2l = reinterpret_cast<const float*>(smem);
    ushort* myp = reinterpret_cast<ushort*>(smem + 8192 + wv * 4608);

    const int jb = jq * 2048 + wv * 512;
    const size_t jstep0 = (size_t)(jb >> 4);
    const int* ap0 = adj + (size_t)(i0 + g8) * 8192 + jb + jc;
    const int* ap1 = ap0 + (size_t)8 * 8192;
    const int* ap2 = ap0 + (size_t)16 * 8192;
    const int* ap3 = ap0 + (size_t)24 * 8192;

    f32x16 acc0 = {0.f,0.f,0.f,0.f,0.f,0.f,0.f,0.f,0.f,0.f,0.f,0.f,0.f,0.f,0.f,0.f};
    f32x16 acc1 = {0.f,0.f,0.f,0.f,0.f,0.f,0.f,0.f,0.f,0.f,0.f,0.f,0.f,0.f,0.f,0.f};
    float rs0 = 0.f, rs1 = 0.f, rs2 = 0.f, rs3 = 0.f;

    for (int ms = 0; ms < 16; ++ms) {
        const int jo = ms * 32;
        // coalesced adj: 4 instrs, each 8 rows x 128B contiguous
        const int4 a0 = *reinterpret_cast<const int4*>(ap0 + jo);
        const int4 a1 = *reinterpret_cast<const int4*>(ap1 + jo);
        const int4 a2 = *reinterpret_cast<const int4*>(ap2 + jo);
        const int4 a3 = *reinterpret_cast<const int4*>(ap3 + jo);
        const float4 sv = *reinterpret_cast<const float4*>(&s2l[wv * 512 + jo + jc]);

        PGRP(0, a0, rs0)
        PGRP(1, a1, rs1)
        PGRP(2, a2, rs2)
        PGRP(3, a3, rs3)

        // two MFMA K-steps from the transposed tile + packed A-frags
#pragma unroll
        for (int ks = 0; ks < 2; ++ks) {
            const size_t js = jstep0 + ms * 2 + ks;
            const bf16x8 ah0 = *reinterpret_cast<const bf16x8*>(&pw_hi[(js * 2 + 0) * 512 + l * 8]);
            const bf16x8 al0 = *reinterpret_cast<const bf16x8*>(&pw_lo[(js * 2 + 0) * 512 + l * 8]);
            const bf16x8 ah1 = *reinterpret_cast<const bf16x8*>(&pw_hi[(js * 2 + 1) * 512 + l * 8]);
            const bf16x8 al1 = *reinterpret_cast<const bf16x8*>(&pw_lo[(js * 2 + 1) * 512 + l * 8]);
            union { bf16x8 v; ushort4 q[2]; } bh;
            bh.q[0] = *reinterpret_cast<const ushort4*>(&myp[row * 36 + ks * 16 + kh * 8]);
            bh.q[1] = *reinterpret_cast<const ushort4*>(&myp[row * 36 + ks * 16 + kh * 8 + 4]);
            acc0 = __builtin_amdgcn_mfma_f32_32x32x16_bf16(ah0, bh.v, acc0, 0, 0, 0);
            acc0 = __builtin_amdgcn_mfma_f32_32x32x16_bf16(al0, bh.v, acc0, 0, 0, 0);
            acc1 = __builtin_amdgcn_mfma_f32_32x32x16_bf16(ah1, bh.v, acc1, 0, 0, 0);
            acc1 = __builtin_amdgcn_mfma_f32_32x32x16_bf16(al1, bh.v, acc1, 0, 0, 0);
        }
    }

    // denominators: exact f32, reduced over the 8 lanes of each j-group
#define RED8(RS) RS += __shfl_xor(RS, 1); RS += __shfl_xor(RS, 2); RS += __shfl_xor(RS, 4);
    RED8(rs0) RED8(rs1) RED8(rs2) RED8(rs3)
    if ((l & 7) == 0) {
        atomicAdd(&pden[i0 +  0 + g8], rs0);
        atomicAdd(&pden[i0 +  8 + g8], rs1);
        atomicAdd(&pden[i0 + 16 + g8], rs2);
        atomicAdd(&pden[i0 + 24 + g8], rs3);
    }

    // cross-wave acc reduce (slds aliases smem) then atomic flush
    __syncthreads();
    float* slds = reinterpret_cast<float*>(smem);      // [3][2][64][16]
    if (wv != 0) {
        float4* d0 = reinterpret_cast<float4*>(&slds[(((wv - 1) * 2 + 0) * 64 + l) * 16]);
        float4* d1 = reinterpret_cast<float4*>(&slds[(((wv - 1) * 2 + 1) * 64 + l) * 16]);
#pragma unroll
        for (int g = 0; g < 4; ++g) {
            d0[g] = make_float4(acc0[g*4+0], acc0[g*4+1], acc0[g*4+2], acc0[g*4+3]);
            d1[g] = make_float4(acc1[g*4+0], acc1[g*4+1], acc1[g*4+2], acc1[g*4+3]);
        }
    }
    __syncthreads();
    if (wv == 0) {
#pragma unroll
        for (int s = 0; s < 3; ++s) {
            const float4* s0 = reinterpret_cast<const float4*>(&slds[((s * 2 + 0) * 64 + l) * 16]);
            const float4* s1p = reinterpret_cast<const float4*>(&slds[((s * 2 + 1) * 64 + l) * 16]);
#pragma unroll
            for (int g = 0; g < 4; ++g) {
                const float4 v0 = s0[g], v1 = s1p[g];
                acc0[g*4+0] += v0.x; acc0[g*4+1] += v0.y; acc0[g*4+2] += v0.z; acc0[g*4+3] += v0.w;
                acc1[g*4+0] += v1.x; acc1[g*4+1] += v1.y; acc1[g*4+2] += v1.z; acc1[g*4+3] += v1.w;
            }
        }
        // D layout (32x32): col=l&31 -> node row; feat-in-half = j + 8g + 4kh
        float* pb = pacc + (size_t)(i0 + row) * 64;
#pragma unroll
        for (int g = 0; g < 4; ++g) {
#pragma unroll
            for (int j = 0; j < 4; ++j) {
                const int f = j + 8 * g + 4 * kh;
                atomicAdd(pb + f,      acc0[g*4+j]);
                atomicAdd(pb + 32 + f, acc1[g*4+j]);
            }
        }
    }
}

// ---------------- kernel 3: finish (divide + ELU) ----------------
__global__ __launch_bounds__(256) void k3_fin(
    const float* __restrict__ pacc, const float* __restrict__ pden,
    float* __restrict__ out)
{
    const int idx = blockIdx.x * 256 + threadIdx.x;   // 131072 float4-groups
    const int row = idx >> 4;
    const float inv = 1.0f / pden[row];
    const float4 v = reinterpret_cast<const float4*>(pacc)[idx];
    float4 o; float x;
    x = v.x * inv; o.x = (x > 0.f) ? x : expm1f(x);
    x = v.y * inv; o.y = (x > 0.f) ? x : expm1f(x);
    x = v.z * inv; o.z = (x > 0.f) ? x : expm1f(x);
    x = v.w * inv; o.w = (x > 0.f) ? x : expm1f(x);
    reinterpret_cast<float4*>(out)[idx] = o;
}

extern "C" void kernel_launch(void* const* d_in, const int* in_sizes, int n_in,
                              void* d_out, int out_size, void* d_ws, size_t ws_size,
                              hipStream_t stream) {
    const float* h   = (const float*)d_in[0];
    const int*   adj = (const int*)d_in[1];
    const float* W   = (const float*)d_in[2];
    const float* a   = (const float*)d_in[3];
    float* out = (float*)d_out;

    float*  s1    = (float*)d_ws;                  // 8192 f32
    float*  s2    = s1 + 8192;                     // 8192 f32 (log2e-scaled)
    ushort* pw_hi = (ushort*)(s2 + 8192);          // 512 jsteps x 2 ft x 512 ushorts (1MB)
    ushort* pw_lo = pw_hi + 512 * 1024;            // 1MB
    float*  pacc  = (float*)(pw_lo + 512 * 1024);  // [8192][64] f32
    float*  pden  = pacc + 8192 * 64;              // [8192] f32

    hipMemsetAsync(pacc, 0, (8192 * 64 + 8192) * sizeof(float), stream);
    hipLaunchKernelGGL(k1_wh, dim3(512), dim3(256), 0, stream,
                       h, W, a, s1, s2, pw_hi, pw_lo);
    hipLaunchKernelGGL(k2_attn, dim3(1024), dim3(256), 0, stream,
                       adj, s1, s2, pw_hi, pw_lo, pacc, pden);
    hipLaunchKernelGGL(k3_fin, dim3(512), dim3(256), 0, stream,
                       pacc, pden, out);
}